// Round 11
// baseline (398.340 us; speedup 1.0000x reference)
//
#include <hip/hip_runtime.h>

typedef unsigned short u16;
typedef unsigned int   u32;
typedef __attribute__((ext_vector_type(8))) short bf16x8;   // 8 bf16 in 4 VGPRs
typedef __attribute__((ext_vector_type(4))) float f32x4;

__device__ inline float bf2f(u16 u) { return __uint_as_float(((u32)u) << 16); }
__device__ inline u16 f2bf(float f) {
  u32 u = __float_as_uint(f);
  return (u16)((u + 0x7FFFu + ((u >> 16) & 1u)) >> 16);   // RNE
}

__device__ inline void gld_lds16(const u16* g, u16* l) {
  __builtin_amdgcn_global_load_lds((const __attribute__((address_space(1))) void*)g,
                                   (__attribute__((address_space(3))) void*)l,
                                   16, 0, 0);
}

// ---- f32 -> bf16 conversion of the 5 GEMM operand tensors (vec4) ----
__global__ __launch_bounds__(256) void cvt_k(
    const float* __restrict__ hs, const float* __restrict__ w_in,
    const float* __restrict__ w_x, const float* __restrict__ w_dt,
    const float* __restrict__ w_out,
    u16* __restrict__ hs_b, u16* __restrict__ w_in_b, u16* __restrict__ w_x_b,
    u16* __restrict__ w_dt_b, u16* __restrict__ w_out_b)
{
  u32 v = blockIdx.x * 256 + threadIdx.x;   // vec4 index, total 2179072
  const float* s; u16* d; u32 loc;
  if      (v < 524288u)  { s = hs;    d = hs_b;    loc = v; }
  else if (v < 1572864u) { s = w_in;  d = w_in_b;  loc = v - 524288u; }
  else if (v < 1622016u) { s = w_x;   d = w_x_b;   loc = v - 1572864u; }
  else if (v < 1654784u) { s = w_dt;  d = w_dt_b;  loc = v - 1622016u; }
  else                   { s = w_out; d = w_out_b; loc = v - 1654784u; }
  float4 f = ((const float4*)s)[loc];
  ushort4 o;
  o.x = f2bf(f.x); o.y = f2bf(f.y); o.z = f2bf(f.z); o.w = f2bf(f.w);
  ((ushort4*)d)[loc] = o;
}

// C = A (MxK bf16, lda) * B^T (B NxK bf16 row-major, ldb), 128x128 tile, BK=32.
// EPI==0: bf16. EPI==1: f32 softplus(acc+bias[col]). EPI==3: f32 partial at +z*M*ldc.
template <int EPI>
__global__ __launch_bounds__(256) void gemm_bt(
    const u16* __restrict__ A, int lda,
    const u16* __restrict__ B, int ldb,
    void* __restrict__ C, int ldc,
    int M, int N, int Klen,
    const float* __restrict__ bias)
{
  __shared__ u16 sA[128 * 32];
  __shared__ u16 sB[128 * 32];
  const int tid  = threadIdx.x;
  const int wave = tid >> 6, lane = tid & 63;
  const int row0 = blockIdx.x * 128, col0 = blockIdx.y * 128;
  const int kbase = blockIdx.z * Klen;
  const int r  = lane >> 2, c8 = (lane & 3) * 8;
  const int wm = (wave >> 1) * 64, wn = (wave & 1) * 64;
  const int tm = lane & 15, quad = lane >> 4;

  f32x4 acc[4][4];
#pragma unroll
  for (int i = 0; i < 4; ++i)
#pragma unroll
    for (int j = 0; j < 4; ++j) acc[i][j] = f32x4{0.f, 0.f, 0.f, 0.f};

  for (int k0 = kbase; k0 < kbase + Klen; k0 += 32) {
    for (int s = wave; s < 8; s += 4) {
      const u16* ga = A + (size_t)(row0 + s * 16 + r) * lda + (k0 + c8);
      gld_lds16(ga, &sA[s * 512 + lane * 8]);
      int br = col0 + s * 16 + r; br = br < N ? br : N - 1;
      const u16* gb = B + (size_t)br * ldb + (k0 + c8);
      gld_lds16(gb, &sB[s * 512 + lane * 8]);
    }
    __syncthreads();
    bf16x8 af[4], bfv[4];
#pragma unroll
    for (int i = 0; i < 4; ++i) af[i]  = *(const bf16x8*)&sA[(wm + i * 16 + tm) * 32 + quad * 8];
#pragma unroll
    for (int j = 0; j < 4; ++j) bfv[j] = *(const bf16x8*)&sB[(wn + j * 16 + tm) * 32 + quad * 8];
#pragma unroll
    for (int i = 0; i < 4; ++i)
#pragma unroll
      for (int j = 0; j < 4; ++j)
        acc[i][j] = __builtin_amdgcn_mfma_f32_16x16x32_bf16(af[i], bfv[j], acc[i][j], 0, 0, 0);
    __syncthreads();
  }

  const size_t zoff = (size_t)blockIdx.z * M * ldc;
#pragma unroll
  for (int j = 0; j < 4; ++j) {
    int col = col0 + wn + j * 16 + tm;
    if (col >= N) continue;
#pragma unroll
    for (int i = 0; i < 4; ++i) {
      int rb = row0 + wm + i * 16 + quad * 4;
      f32x4 v = acc[i][j];
#pragma unroll
      for (int t = 0; t < 4; ++t) {
        float f = v[t];
        size_t idx = (size_t)(rb + t) * ldc + col;
        if (EPI == 1) {
          f += bias[col];
          f = (f > 20.f) ? f : log1pf(__expf(f));
          ((float*)C)[idx] = f;
        } else if (EPI == 3) {
          ((float*)C)[zoff + idx] = f;
        } else {
          ((u16*)C)[idx] = f2bf(f);
        }
      }
    }
  }
}

// sum KS split-K partials (each `total` f32), vec4, f32 out.
__global__ __launch_bounds__(256) void red_k(
    const float* __restrict__ part, float* __restrict__ out, int total, int KS)
{
  int i = blockIdx.x * 256 + threadIdx.x;
  f32x4 a = ((const f32x4*)part)[i];
  for (int ks = 1; ks < KS; ++ks)
    a += ((const f32x4*)(part + (size_t)ks * total))[i];
  ((f32x4*)out)[i] = a;
}

// ===== fused row kernel: conv+silu + x_proj, block = 8 rows (256 blocks) =====
__global__ __launch_bounds__(256) void row_fuse_k(
    const u16* __restrict__ xz,      // (2048,4096) bf16, x = cols 0..2047
    const float* __restrict__ cw,    // (2048,4)
    const float* __restrict__ cb,    // (2048,)
    const u16* __restrict__ w_x_b,   // (96,2048) bf16
    u16* __restrict__ xc,            // out (2048,2048) bf16
    u16* __restrict__ xdbl)          // out (2048,96) bf16
{
  __shared__ u16   xrow[8][2048];    // 32 KB conv+silu output (bf16)
  __shared__ u16   we[4][2048];      // 16 KB w_x chunk
  __shared__ float xdl[8][96];       // 3 KB x_proj output
  const int tid = threadIdx.x;
  const int r0 = blockIdx.x * 8;     // blocks of 8 rows never straddle the b boundary

  // stage 1: conv + silu (coalesced over d)
  for (int i = tid; i < 8 * 2048; i += 256) {
    int ri = i >> 11, d = i & 2047;
    int r = r0 + ri, l = r & 1023;
    float acc = cb[d];
#pragma unroll
    for (int k = 0; k < 4; ++k) {
      int ll = l - 3 + k;
      if (ll >= 0) acc += bf2f(xz[(size_t)(r - 3 + k) * 4096 + d]) * cw[d * 4 + k];
    }
    float s = acc / (1.f + __expf(-acc));
    u16 sb = f2bf(s);
    xrow[ri][d] = sb;
    xc[(size_t)r * 2048 + d] = sb;
  }
  __syncthreads();

  // stage 2: x_proj (96 outputs per row), e-chunks of 4, LDS-staged weights
  const int wave = tid >> 6, lane = tid & 63;
  const int ra = wave * 2, rb2 = wave * 2 + 1;
  for (int ec = 0; ec < 96; ec += 4) {
    for (int i = tid; i < 4 * 2048; i += 256)
      we[i >> 11][i & 2047] = w_x_b[(size_t)(ec + (i >> 11)) * 2048 + (i & 2047)];
    __syncthreads();
#pragma unroll
    for (int e4 = 0; e4 < 4; ++e4) {
      float p0 = 0.f, p1 = 0.f;
      for (int k8 = lane; k8 < 256; k8 += 64) {
        bf16x8 wv = *(const bf16x8*)&we[e4][k8 * 8];
        bf16x8 a0 = *(const bf16x8*)&xrow[ra][k8 * 8];
        bf16x8 a1 = *(const bf16x8*)&xrow[rb2][k8 * 8];
#pragma unroll
        for (int q = 0; q < 8; ++q) {
          float wq = bf2f((u16)wv[q]);
          p0 = fmaf(bf2f((u16)a0[q]), wq, p0);
          p1 = fmaf(bf2f((u16)a1[q]), wq, p1);
        }
      }
#pragma unroll
      for (int s = 32; s; s >>= 1) { p0 += __shfl_xor(p0, s, 64); p1 += __shfl_xor(p1, s, 64); }
      if (lane == 0) { xdl[ra][ec + e4] = p0; xdl[rb2][ec + e4] = p1; }
    }
    __syncthreads();
  }

  // stage 3: write xdbl (bf16, row stride 96)
  for (int i = tid; i < 8 * 96; i += 256) {
    int ri = i / 96, e = i - ri * 96;
    xdbl[(size_t)(r0 + ri) * 96 + e] = f2bf(xdl[ri][e]);
  }
}

// ===== fused selective scan: pass1 + in-block combine + pass3 (one kernel) =====
// block = 8 channels x 32 segments of 32 timesteps; grid (256, B)
__global__ __launch_bounds__(256) void scan_fused_k(
    const float* __restrict__ dtf,   // (2048,2048) f32 post-softplus
    const u16* __restrict__ xdbl,    // (2048,96) bf16: [dt_r|Bm|Cm]
    u16* xcy,                        // (2048,2048) x_conv in / y out (in place)
    const u16* __restrict__ xz,      // (2048,4096) bf16, z at col+2048
    const float* __restrict__ A_log, // (2048,16) f32
    const float* __restrict__ Dw)    // (2048,)
{
  // padded layout: ch stride 545 floats, seg stride 17 -> combine reads conflict-free
  __shared__ float sm[2 * 8 * 545];            // 34.9 KB: hend | P
  float* hend = sm;
  float* Pl   = sm + 8 * 545;
  const int tid = threadIdx.x;
  const int ch = tid & 7, seg = tid >> 3;
  const int d = blockIdx.x * 8 + ch;
  const int b = blockIdx.y;
  float cA[16];
#pragma unroll
  for (int n = 0; n < 16; ++n) cA[n] = -__expf(A_log[d * 16 + n]);
  const size_t rbase = (size_t)b * 1024 + seg * 32;

  // pass 1: local scan, h0 = 0
  float h[16];
#pragma unroll
  for (int n = 0; n < 16; ++n) h[n] = 0.f;
  float sdt = 0.f;
  for (int t = 0; t < 32; ++t) {
    size_t row = rbase + t;
    float dt = dtf[row * 2048 + d];
    float xv = bf2f(xcy[row * 2048 + d]);
    bf16x8 Bv0 = *(const bf16x8*)(xdbl + row * 96 + 64);
    bf16x8 Bv1 = *(const bf16x8*)(xdbl + row * 96 + 72);
    float dBu = dt * xv;
    sdt += dt;
#pragma unroll
    for (int n = 0; n < 16; ++n) {
      float Bn = bf2f((u16)(n < 8 ? Bv0[n] : Bv1[n - 8]));
      h[n] = fmaf(__expf(dt * cA[n]), h[n], dBu * Bn);
    }
  }
  const int base = ch * 545 + seg * 17;
#pragma unroll
  for (int n = 0; n < 16; ++n) { hend[base + n] = h[n]; Pl[base + n] = __expf(cA[n] * sdt); }
  __syncthreads();

  // pass 2: in-block prefix combine -> h_start for this segment
  float c[16];
#pragma unroll
  for (int n = 0; n < 16; ++n) c[n] = 0.f;
  for (int j = 0; j < seg; ++j) {
    const int bj = ch * 545 + j * 17;
#pragma unroll
    for (int n = 0; n < 16; ++n) c[n] = fmaf(Pl[bj + n], c[n], hend[bj + n]);
  }

  // pass 3: rescan with true h_start; fuse y = C.h + x*D, silu(z) gate; y -> xcy
  float Dd = Dw[d];
#pragma unroll
  for (int n = 0; n < 16; ++n) h[n] = c[n];
  for (int t = 0; t < 32; ++t) {
    size_t row = rbase + t;
    float dt = dtf[row * 2048 + d];
    float xv = bf2f(xcy[row * 2048 + d]);
    float zv = bf2f(xz[row * 4096 + 2048 + d]);
    bf16x8 Bv0 = *(const bf16x8*)(xdbl + row * 96 + 64);
    bf16x8 Bv1 = *(const bf16x8*)(xdbl + row * 96 + 72);
    bf16x8 Cv0 = *(const bf16x8*)(xdbl + row * 96 + 80);
    bf16x8 Cv1 = *(const bf16x8*)(xdbl + row * 96 + 88);
    float dBu = dt * xv;
    float y = xv * Dd;
#pragma unroll
    for (int n = 0; n < 16; ++n) {
      float Bn = bf2f((u16)(n < 8 ? Bv0[n] : Bv1[n - 8]));
      float Cn = bf2f((u16)(n < 8 ? Cv0[n] : Cv1[n - 8]));
      h[n] = fmaf(__expf(dt * cA[n]), h[n], dBu * Bn);
      y = fmaf(h[n], Cn, y);
    }
    float sig = 1.f / (1.f + __expf(-zv));
    xcy[row * 2048 + d] = f2bf(y * (zv * sig));
  }
}

extern "C" void kernel_launch(void* const* d_in, const int* in_sizes, int n_in,
                              void* d_out, int out_size, void* d_ws, size_t ws_size,
                              hipStream_t stream)
{
  const float* hs    = (const float*)d_in[0];   // (2,1024,1024)
  const float* w_in  = (const float*)d_in[1];   // (4096,1024)
  const float* cw    = (const float*)d_in[2];   // (2048,1,4)
  const float* cb    = (const float*)d_in[3];   // (2048,)
  const float* w_x   = (const float*)d_in[4];   // (96,2048)
  const float* w_dt  = (const float*)d_in[5];   // (2048,64)
  const float* b_dt  = (const float*)d_in[6];   // (2048,)
  const float* A_log = (const float*)d_in[7];   // (2048,16)
  const float* Dw    = (const float*)d_in[8];   // (2048,)
  const float* w_out = (const float*)d_in[9];   // (1024,2048)

  // Workspace ~90.6 MB, no overlays.
  char* p = (char*)d_ws;
  u16*   hs_b   = (u16*)p;  p += (size_t)2097152 * 2;       // 4 MB
  u16*   w_in_b = (u16*)p;  p += (size_t)4194304 * 2;       // 8 MB
  u16*   w_x_b  = (u16*)p;  p += (size_t)196608 * 2;        // 384 KB
  u16*   w_dt_b = (u16*)p;  p += (size_t)131072 * 2;        // 256 KB
  u16*   w_out_b= (u16*)p;  p += (size_t)2097152 * 2;       // 4 MB
  u16*   xz     = (u16*)p;  p += (size_t)2048 * 4096 * 2;   // 16 MB
  u16*   xc     = (u16*)p;  p += (size_t)2048 * 2048 * 2;   // 8 MB (also y, in-place)
  u16*   xdbl   = (u16*)p;  p += (size_t)2048 * 96 * 2;     // 384 KB
  float* dtf    = (float*)p;p += (size_t)2048 * 2048 * 4;   // 16 MB
  float* pout   = (float*)p;                                // 33.5 MB split-K partials
  float* out    = (float*)d_out;

  // 1) convert f32 -> bf16 GEMM operands
  cvt_k<<<8512, 256, 0, stream>>>(hs, w_in, w_x, w_dt, w_out,
                                  hs_b, w_in_b, w_x_b, w_dt_b, w_out_b);
  // 2) xz = hs @ in_proj_w^T         (2048 x 4096, K=1024)
  gemm_bt<0><<<dim3(16, 32, 1), 256, 0, stream>>>(hs_b, 1024, w_in_b, 1024, xz, 4096, 2048, 4096, 1024, nullptr);
  // 3) fused conv+silu+x_proj        -> xc, xdbl
  row_fuse_k<<<256, 256, 0, stream>>>(xz, cw, cb, w_x_b, xc, xdbl);
  // 4) dt = softplus(x_dbl[:, :64] @ dt_proj_w^T + b)   (2048 x 2048, K=64)
  gemm_bt<1><<<dim3(16, 16, 1), 256, 0, stream>>>(xdbl, 96, w_dt_b, 64, dtf, 2048, 2048, 2048, 64, b_dt);
  // 5) fused selective scan (pass1 + combine + pass3), y -> xc in place
  scan_fused_k<<<dim3(256, 2), 256, 0, stream>>>(dtf, xdbl, xc, xz, A_log, Dw);
  // 6) out = y @ out_proj_w^T        (2048 x 1024, K=2048) — split-K x4
  gemm_bt<3><<<dim3(16, 8, 4), 256, 0, stream>>>(xc, 2048, w_out_b, 2048, pout, 1024, 2048, 1024, 512, nullptr);
  // 7) reduce split-K partials -> d_out (f32)
  red_k<<<2048, 256, 0, stream>>>(pout, out, 2097152, 4);
}

// Round 12
// 272.860 us; speedup vs baseline: 1.4599x; 1.4599x over previous
//
#include <hip/hip_runtime.h>

typedef unsigned short u16;
typedef unsigned int   u32;
typedef __attribute__((ext_vector_type(8))) short bf16x8;   // 8 bf16 in 4 VGPRs
typedef __attribute__((ext_vector_type(4))) float f32x4;

__device__ inline float bf2f(u16 u) { return __uint_as_float(((u32)u) << 16); }
__device__ inline u16 f2bf(float f) {
  u32 u = __float_as_uint(f);
  return (u16)((u + 0x7FFFu + ((u >> 16) & 1u)) >> 16);   // RNE
}

__device__ inline void gld_lds16(const u16* g, u16* l) {
  __builtin_amdgcn_global_load_lds((const __attribute__((address_space(1))) void*)g,
                                   (__attribute__((address_space(3))) void*)l,
                                   16, 0, 0);
}

// ---- f32 -> bf16 conversion of the 5 GEMM operand tensors (vec4) ----
__global__ __launch_bounds__(256) void cvt_k(
    const float* __restrict__ hs, const float* __restrict__ w_in,
    const float* __restrict__ w_x, const float* __restrict__ w_dt,
    const float* __restrict__ w_out,
    u16* __restrict__ hs_b, u16* __restrict__ w_in_b, u16* __restrict__ w_x_b,
    u16* __restrict__ w_dt_b, u16* __restrict__ w_out_b)
{
  u32 v = blockIdx.x * 256 + threadIdx.x;   // vec4 index, total 2179072
  const float* s; u16* d; u32 loc;
  if      (v < 524288u)  { s = hs;    d = hs_b;    loc = v; }
  else if (v < 1572864u) { s = w_in;  d = w_in_b;  loc = v - 524288u; }
  else if (v < 1622016u) { s = w_x;   d = w_x_b;   loc = v - 1572864u; }
  else if (v < 1654784u) { s = w_dt;  d = w_dt_b;  loc = v - 1622016u; }
  else                   { s = w_out; d = w_out_b; loc = v - 1654784u; }
  float4 f = ((const float4*)s)[loc];
  ushort4 o;
  o.x = f2bf(f.x); o.y = f2bf(f.y); o.z = f2bf(f.z); o.w = f2bf(f.w);
  ((ushort4*)d)[loc] = o;
}

// C = A (MxK bf16, lda) * B^T (B NxK bf16 row-major, ldb), 128x128 tile, BK=32.
// EPI==0: bf16. EPI==1: f32 softplus(acc+bias[col]). EPI==3: f32 partial at +z*M*ldc.
template <int EPI>
__global__ __launch_bounds__(256) void gemm_bt(
    const u16* __restrict__ A, int lda,
    const u16* __restrict__ B, int ldb,
    void* __restrict__ C, int ldc,
    int M, int N, int Klen,
    const float* __restrict__ bias)
{
  __shared__ u16 sA[128 * 32];
  __shared__ u16 sB[128 * 32];
  const int tid  = threadIdx.x;
  const int wave = tid >> 6, lane = tid & 63;
  const int row0 = blockIdx.x * 128, col0 = blockIdx.y * 128;
  const int kbase = blockIdx.z * Klen;
  const int r  = lane >> 2, c8 = (lane & 3) * 8;
  const int wm = (wave >> 1) * 64, wn = (wave & 1) * 64;
  const int tm = lane & 15, quad = lane >> 4;

  f32x4 acc[4][4];
#pragma unroll
  for (int i = 0; i < 4; ++i)
#pragma unroll
    for (int j = 0; j < 4; ++j) acc[i][j] = f32x4{0.f, 0.f, 0.f, 0.f};

  for (int k0 = kbase; k0 < kbase + Klen; k0 += 32) {
    for (int s = wave; s < 8; s += 4) {
      const u16* ga = A + (size_t)(row0 + s * 16 + r) * lda + (k0 + c8);
      gld_lds16(ga, &sA[s * 512 + lane * 8]);
      int br = col0 + s * 16 + r; br = br < N ? br : N - 1;
      const u16* gb = B + (size_t)br * ldb + (k0 + c8);
      gld_lds16(gb, &sB[s * 512 + lane * 8]);
    }
    __syncthreads();
    bf16x8 af[4], bfv[4];
#pragma unroll
    for (int i = 0; i < 4; ++i) af[i]  = *(const bf16x8*)&sA[(wm + i * 16 + tm) * 32 + quad * 8];
#pragma unroll
    for (int j = 0; j < 4; ++j) bfv[j] = *(const bf16x8*)&sB[(wn + j * 16 + tm) * 32 + quad * 8];
#pragma unroll
    for (int i = 0; i < 4; ++i)
#pragma unroll
      for (int j = 0; j < 4; ++j)
        acc[i][j] = __builtin_amdgcn_mfma_f32_16x16x32_bf16(af[i], bfv[j], acc[i][j], 0, 0, 0);
    __syncthreads();
  }

  const size_t zoff = (size_t)blockIdx.z * M * ldc;
#pragma unroll
  for (int j = 0; j < 4; ++j) {
    int col = col0 + wn + j * 16 + tm;
    if (col >= N) continue;
#pragma unroll
    for (int i = 0; i < 4; ++i) {
      int rb = row0 + wm + i * 16 + quad * 4;
      f32x4 v = acc[i][j];
#pragma unroll
      for (int t = 0; t < 4; ++t) {
        float f = v[t];
        size_t idx = (size_t)(rb + t) * ldc + col;
        if (EPI == 1) {
          f += bias[col];
          f = (f > 20.f) ? f : log1pf(__expf(f));
          ((float*)C)[idx] = f;
        } else if (EPI == 3) {
          ((float*)C)[zoff + idx] = f;
        } else {
          ((u16*)C)[idx] = f2bf(f);
        }
      }
    }
  }
}

// sum KS split-K partials (each `total` f32), vec4. OUTBF==1: bf16 out, else f32.
template <int OUTBF>
__global__ __launch_bounds__(256) void red_k(
    const float* __restrict__ part, void* __restrict__ out, int total, int KS)
{
  int i = blockIdx.x * 256 + threadIdx.x;
  f32x4 a = ((const f32x4*)part)[i];
  for (int ks = 1; ks < KS; ++ks)
    a += ((const f32x4*)(part + (size_t)ks * total))[i];
  if (OUTBF) {
    ushort4 o; o.x = f2bf(a[0]); o.y = f2bf(a[1]); o.z = f2bf(a[2]); o.w = f2bf(a[3]);
    ((ushort4*)out)[i] = o;
  } else {
    ((f32x4*)out)[i] = a;
  }
}

// depthwise causal conv (K=4) + bias + silu. xz: (B*L) x 4096 bf16, x = cols 0..2047
__global__ __launch_bounds__(256) void conv_silu_k(
    const u16* __restrict__ xz, const float* __restrict__ cw,
    const float* __restrict__ cb, u16* __restrict__ xc)
{
  int gid = blockIdx.x * 256 + threadIdx.x;
  int d = gid & 2047;
  int row = gid >> 11;        // b*1024 + l
  int l = row & 1023;
  float acc = cb[d];
#pragma unroll
  for (int k = 0; k < 4; ++k) {
    int ll = l - 3 + k;
    if (ll >= 0)
      acc += bf2f(xz[(size_t)(row - 3 + k) * 4096 + d]) * cw[d * 4 + k];
  }
  float s = acc / (1.f + __expf(-acc));
  xc[(size_t)row * 2048 + d] = f2bf(s);
}

// ===== fused selective scan: pass1 + in-block combine + pass3 (one kernel) =====
// block = 8 channels x 32 segments of 32 timesteps; grid (256, B)
// (validated round 11: absmax identical to 3-pass version)
__global__ __launch_bounds__(256) void scan_fused_k(
    const float* __restrict__ dtf,   // (2048,2048) f32 post-softplus
    const u16* __restrict__ xdbl,    // (2048,96) bf16: [dt_r|Bm|Cm]
    u16* xcy,                        // (2048,2048) x_conv in / y out (in place)
    const u16* __restrict__ xz,      // (2048,4096) bf16, z at col+2048
    const float* __restrict__ A_log, // (2048,16) f32
    const float* __restrict__ Dw)    // (2048,)
{
  // padded layout: ch stride 545 floats, seg stride 17 -> combine reads conflict-free
  __shared__ float sm[2 * 8 * 545];            // 34.9 KB: hend | P
  float* hend = sm;
  float* Pl   = sm + 8 * 545;
  const int tid = threadIdx.x;
  const int ch = tid & 7, seg = tid >> 3;
  const int d = blockIdx.x * 8 + ch;
  const int b = blockIdx.y;
  float cA[16];
#pragma unroll
  for (int n = 0; n < 16; ++n) cA[n] = -__expf(A_log[d * 16 + n]);
  const size_t rbase = (size_t)b * 1024 + seg * 32;

  // pass 1: local scan, h0 = 0
  float h[16];
#pragma unroll
  for (int n = 0; n < 16; ++n) h[n] = 0.f;
  float sdt = 0.f;
  for (int t = 0; t < 32; ++t) {
    size_t row = rbase + t;
    float dt = dtf[row * 2048 + d];
    float xv = bf2f(xcy[row * 2048 + d]);
    bf16x8 Bv0 = *(const bf16x8*)(xdbl + row * 96 + 64);
    bf16x8 Bv1 = *(const bf16x8*)(xdbl + row * 96 + 72);
    float dBu = dt * xv;
    sdt += dt;
#pragma unroll
    for (int n = 0; n < 16; ++n) {
      float Bn = bf2f((u16)(n < 8 ? Bv0[n] : Bv1[n - 8]));
      h[n] = fmaf(__expf(dt * cA[n]), h[n], dBu * Bn);
    }
  }
  const int base = ch * 545 + seg * 17;
#pragma unroll
  for (int n = 0; n < 16; ++n) { hend[base + n] = h[n]; Pl[base + n] = __expf(cA[n] * sdt); }
  __syncthreads();

  // pass 2: in-block prefix combine -> h_start for this segment
  float c[16];
#pragma unroll
  for (int n = 0; n < 16; ++n) c[n] = 0.f;
  for (int j = 0; j < seg; ++j) {
    const int bj = ch * 545 + j * 17;
#pragma unroll
    for (int n = 0; n < 16; ++n) c[n] = fmaf(Pl[bj + n], c[n], hend[bj + n]);
  }

  // pass 3: rescan with true h_start; fuse y = C.h + x*D, silu(z) gate; y -> xcy
  float Dd = Dw[d];
#pragma unroll
  for (int n = 0; n < 16; ++n) h[n] = c[n];
  for (int t = 0; t < 32; ++t) {
    size_t row = rbase + t;
    float dt = dtf[row * 2048 + d];
    float xv = bf2f(xcy[row * 2048 + d]);
    float zv = bf2f(xz[row * 4096 + 2048 + d]);
    bf16x8 Bv0 = *(const bf16x8*)(xdbl + row * 96 + 64);
    bf16x8 Bv1 = *(const bf16x8*)(xdbl + row * 96 + 72);
    bf16x8 Cv0 = *(const bf16x8*)(xdbl + row * 96 + 80);
    bf16x8 Cv1 = *(const bf16x8*)(xdbl + row * 96 + 88);
    float dBu = dt * xv;
    float y = xv * Dd;
#pragma unroll
    for (int n = 0; n < 16; ++n) {
      float Bn = bf2f((u16)(n < 8 ? Bv0[n] : Bv1[n - 8]));
      float Cn = bf2f((u16)(n < 8 ? Cv0[n] : Cv1[n - 8]));
      h[n] = fmaf(__expf(dt * cA[n]), h[n], dBu * Bn);
      y = fmaf(h[n], Cn, y);
    }
    float sig = 1.f / (1.f + __expf(-zv));
    xcy[row * 2048 + d] = f2bf(y * (zv * sig));
  }
}

extern "C" void kernel_launch(void* const* d_in, const int* in_sizes, int n_in,
                              void* d_out, int out_size, void* d_ws, size_t ws_size,
                              hipStream_t stream)
{
  const float* hs    = (const float*)d_in[0];   // (2,1024,1024)
  const float* w_in  = (const float*)d_in[1];   // (4096,1024)
  const float* cw    = (const float*)d_in[2];   // (2048,1,4)
  const float* cb    = (const float*)d_in[3];   // (2048,)
  const float* w_x   = (const float*)d_in[4];   // (96,2048)
  const float* w_dt  = (const float*)d_in[5];   // (2048,64)
  const float* b_dt  = (const float*)d_in[6];   // (2048,)
  const float* A_log = (const float*)d_in[7];   // (2048,16)
  const float* Dw    = (const float*)d_in[8];   // (2048,)
  const float* w_out = (const float*)d_in[9];   // (1024,2048)

  // Workspace ~103 MB, no overlays.
  char* p = (char*)d_ws;
  u16*   hs_b   = (u16*)p;  p += (size_t)2097152 * 2;       // 4 MB
  u16*   w_in_b = (u16*)p;  p += (size_t)4194304 * 2;       // 8 MB
  u16*   w_x_b  = (u16*)p;  p += (size_t)196608 * 2;        // 384 KB
  u16*   w_dt_b = (u16*)p;  p += (size_t)131072 * 2;        // 256 KB
  u16*   w_out_b= (u16*)p;  p += (size_t)2097152 * 2;       // 4 MB
  u16*   xz     = (u16*)p;  p += (size_t)2048 * 4096 * 2;   // 16 MB
  u16*   xc     = (u16*)p;  p += (size_t)2048 * 2048 * 2;   // 8 MB (also y, in-place)
  u16*   xdbl   = (u16*)p;  p += (size_t)2048 * 96 * 2;     // 384 KB
  float* dtf    = (float*)p;p += (size_t)2048 * 2048 * 4;   // 16 MB
  float* pout   = (float*)p;p += (size_t)4 * 2048 * 1024 * 4;  // 33.5 MB split-K partials
  float* px     = (float*)p;                                   // 12.6 MB split-K partials
  float* out    = (float*)d_out;

  // 1) convert f32 -> bf16 GEMM operands
  cvt_k<<<8512, 256, 0, stream>>>(hs, w_in, w_x, w_dt, w_out,
                                  hs_b, w_in_b, w_x_b, w_dt_b, w_out_b);
  // 2) xz = hs @ in_proj_w^T         (2048 x 4096, K=1024)
  gemm_bt<0><<<dim3(16, 32, 1), 256, 0, stream>>>(hs_b, 1024, w_in_b, 1024, xz, 4096, 2048, 4096, 1024, nullptr);
  // 3) x = silu(causal_conv(x) + b)
  conv_silu_k<<<16384, 256, 0, stream>>>(xz, cw, cb, xc);
  // 4) x_dbl = x @ x_proj_w^T        (2048 x 96, K=2048) — split-K x16
  gemm_bt<3><<<dim3(16, 1, 16), 256, 0, stream>>>(xc, 2048, w_x_b, 2048, px, 96, 2048, 96, 128, nullptr);
  // 5) reduce x_proj partials -> xdbl (bf16)
  red_k<1><<<192, 256, 0, stream>>>(px, xdbl, 196608, 16);
  // 6) dt = softplus(x_dbl[:, :64] @ dt_proj_w^T + b)   (2048 x 2048, K=64)
  gemm_bt<1><<<dim3(16, 16, 1), 256, 0, stream>>>(xdbl, 96, w_dt_b, 64, dtf, 2048, 2048, 2048, 64, b_dt);
  // 7) fused selective scan (pass1 + combine + pass3), y -> xc in place
  scan_fused_k<<<dim3(256, 2), 256, 0, stream>>>(dtf, xdbl, xc, xz, A_log, Dw);
  // 8) out = y @ out_proj_w^T        (2048 x 1024, K=2048) — split-K x4
  gemm_bt<3><<<dim3(16, 8, 4), 256, 0, stream>>>(xc, 2048, w_out_b, 2048, pout, 1024, 2048, 1024, 512, nullptr);
  // 9) reduce split-K partials -> d_out (f32)
  red_k<0><<<2048, 256, 0, stream>>>(pout, out, 2097152, 4);
}